// Round 4
// baseline (221.115 us; speedup 1.0000x reference)
//
#include <hip/hip_runtime.h>
#include <math.h>

#define D 2048
#define K 8
#define BLOCK 512   // 8 waves; one row per block-iteration, thread owns 4 cols

__device__ __forceinline__ float rcp_fast(float x) {
    return __builtin_amdgcn_rcpf(x);
}

// 0.5*y*(1+tanh(c*(y+0.044715*y^3))) == y * sigmoid(2c*(y + 0.044715*y^3))
__device__ __forceinline__ float gelu_tanh_fast(float y) {
    const float c2 = 1.5957691216057308f; // 2*sqrt(2/pi)
    float w = y * fmaf(0.044715f, y * y, 1.0f);
    return y * rcp_fast(1.0f + __expf(-c2 * w));
}

__device__ __forceinline__ float dot4(const float4& a, const float4& b) {
    return fmaf(a.w, b.w, fmaf(a.z, b.z, fmaf(a.y, b.y, a.x * b.x)));
}

__global__ __launch_bounds__(BLOCK, 8)
void novelty_gelu_kernel(const float* __restrict__ x,
                         const float* __restrict__ P,
                         const float* __restrict__ plog_tau,
                         const float* __restrict__ plog_blend,
                         float* __restrict__ out,
                         int nrows)
{
    // redD[buf][wave*64 + g*8 + j] = partial dot[j] summed over 8-lane group g of wave
    __shared__ float redD[2][BLOCK];
    __shared__ float redS[2][8];      // per-wave ssq partials

    const int tid  = threadIdx.x;
    const int wave = tid >> 6;
    const int lane = tid & 63;
    const int col  = tid * 4;         // this thread's 4 columns

    // ---- P fragments into registers (8 x float4 = 32 VGPR), pre-scale by 1/||P_k|| ----
    float4 pf[K];
    #pragma unroll
    for (int k = 0; k < K; ++k)
        pf[k] = *(const float4*)(P + k * D + col);
    {
        float nk[K];
        #pragma unroll
        for (int k = 0; k < K; ++k) nk[k] = dot4(pf[k], pf[k]);
        #pragma unroll
        for (int m = 1; m < 64; m <<= 1) {
            #pragma unroll
            for (int k = 0; k < K; ++k) nk[k] += __shfl_xor(nk[k], m);
        }
        if (lane == 0) {
            #pragma unroll
            for (int k = 0; k < K; ++k) redD[0][wave * K + k] = nk[k];
        }
        __syncthreads();
        #pragma unroll
        for (int k = 0; k < K; ++k) {
            float s = 0.f;
            #pragma unroll
            for (int w = 0; w < 8; ++w) s += redD[0][w * K + k];
            float inv = 1.0f / fmaxf(sqrtf(s), 1e-8f);
            pf[k].x *= inv; pf[k].y *= inv; pf[k].z *= inv; pf[k].w *= inv;
        }
        __syncthreads();   // redD[0] reused by first row iteration
    }

    const float tau   = __expf(plog_tau[0]);
    const float alpha = 1.0f / (1.0f + __expf(-plog_blend[0]));
    const float oma   = 1.0f - alpha;

    const int stride = gridDim.x;
    int row = blockIdx.x;
    int buf = 0;

    float4 a, b;
    if (row < nrows)
        a = *(const float4*)(x + (size_t)row * D + col);

    while (row < nrows) {
        const int nrow = row + stride;
        if (nrow < nrows)                       // prefetch next row
            b = *(const float4*)(x + (size_t)nrow * D + col);

        // per-thread partials over 4 cols
        float ssq = dot4(a, a);
        float dt[K];
        #pragma unroll
        for (int k = 0; k < K; ++k) dt[k] = dot4(a, pf[k]);

        // 3-step butterfly -> sums over each 8-lane group
        #pragma unroll
        for (int m = 1; m <= 4; m <<= 1) {
            ssq += __shfl_xor(ssq, m);
            #pragma unroll
            for (int k = 0; k < K; ++k) dt[k] += __shfl_xor(dt[k], m);
        }
        // finish ssq to full-wave sum
        ssq += __shfl_xor(ssq, 8);
        ssq += __shfl_xor(ssq, 16);
        ssq += __shfl_xor(ssq, 32);
        if (lane == 0) redS[buf][wave] = ssq;

        // lane j = lane&7 selects dt[j] (7 cndmask)
        float t01 = (lane & 1) ? dt[1] : dt[0];
        float t23 = (lane & 1) ? dt[3] : dt[2];
        float t45 = (lane & 1) ? dt[5] : dt[4];
        float t67 = (lane & 1) ? dt[7] : dt[6];
        float u0  = (lane & 2) ? t23 : t01;
        float u1  = (lane & 2) ? t67 : t45;
        float v   = (lane & 4) ? u1 : u0;
        redD[buf][(wave << 6) + lane] = v;      // linear, conflict-free

        __syncthreads();

        // final reduce: sum over waves (8 strided reads), then over groups (xor 8/16/32),
        // then max over j (xor 1/2/4). Every lane ends with dmax.
        float s = 0.f;
        #pragma unroll
        for (int i = 0; i < 8; ++i) s += redD[buf][(i << 6) + lane];
        s += __shfl_xor(s, 8);
        s += __shfl_xor(s, 16);
        s += __shfl_xor(s, 32);
        float dmax = s;
        dmax = fmaxf(dmax, __shfl_xor(dmax, 1));
        dmax = fmaxf(dmax, __shfl_xor(dmax, 2));
        dmax = fmaxf(dmax, __shfl_xor(dmax, 4));

        const float4 q0 = *(const float4*)&redS[buf][0];   // broadcast reads
        const float4 q1 = *(const float4*)&redS[buf][4];
        float tssq = ((q0.x + q0.y) + (q0.z + q0.w)) + ((q1.x + q1.y) + (q1.z + q1.w));

        const float inv_nx = 1.0f / fmaxf(sqrtf(tssq), 1e-8f);
        float sim = fminf(1.0f, fmaxf(-1.0f, dmax * inv_nx));
        float md  = fminf(fmaxf(1.0f - sim, 0.0f), 2.0f);
        float scale = oma + alpha * (1.0f - __expf(-tau * md));
        scale = fminf(fmaxf(scale, 0.1f), 10.0f);

        // epilogue from registers
        float4 o;
        o.x = gelu_tanh_fast(a.x * scale);
        o.y = gelu_tanh_fast(a.y * scale);
        o.z = gelu_tanh_fast(a.z * scale);
        o.w = gelu_tanh_fast(a.w * scale);
        *(float4*)(out + (size_t)row * D + col) = o;

        a = b;
        row = nrow;
        buf ^= 1;
    }
}

extern "C" void kernel_launch(void* const* d_in, const int* in_sizes, int n_in,
                              void* d_out, int out_size, void* d_ws, size_t ws_size,
                              hipStream_t stream) {
    const float* x  = (const float*)d_in[0];
    const float* P  = (const float*)d_in[1];
    const float* lt = (const float*)d_in[2];
    const float* lb = (const float*)d_in[3];
    float* out = (float*)d_out;

    const int nrows = in_sizes[0] / D;   // 32768
    int grid = nrows < 2048 ? nrows : 2048;

    novelty_gelu_kernel<<<grid, BLOCK, 0, stream>>>(x, P, lt, lb, out, nrows);
}